// Round 1
// 8031.886 us; speedup vs baseline: 1.4836x; 1.4836x over previous
//
#include <hip/hip_runtime.h>

#define B_SZ 32
#define S_LEN 2048
#define I_SZ 256
#define H_SZ 512
#define OUT_MAIN ((size_t)B_SZ * S_LEN * H_SZ)
#define NPER (S_LEN / 2)  // 1024 exchange periods, 2 timesteps each

typedef _Float16 half8 __attribute__((ext_vector_type(8)));
typedef float floatx4 __attribute__((ext_vector_type(4)));
typedef unsigned long long u64;

// ---------------------------------------------------------------------------
// Kernel 1: zero flags, convert W_ih / W_hh / h0 to f16 in ws.
// ---------------------------------------------------------------------------
__global__ void rnn_init(const float* __restrict__ wih, const float* __restrict__ whh,
                         const float* __restrict__ h0,
                         _Float16* __restrict__ wih16, _Float16* __restrict__ whh16,
                         _Float16* __restrict__ h16, unsigned* __restrict__ flags) {
  int idx = blockIdx.x * blockDim.x + threadIdx.x;
  int stride = gridDim.x * blockDim.x;
  if (idx < 128) flags[idx] = 0;  // ws is poisoned every call; must re-zero
  for (int i = idx; i < H_SZ * I_SZ; i += stride) wih16[i] = (_Float16)wih[i];
  for (int i = idx; i < H_SZ * H_SZ; i += stride) whh16[i] = (_Float16)whh[i];
  for (int i = idx; i < B_SZ * H_SZ; i += stride) h16[i] = (_Float16)h0[i];
}

// ---------------------------------------------------------------------------
// Kernel 2: z' = inputs @ W_ih^T + b_ih + b_hh -> d_out in [B,S,H] layout.
// (unchanged — ~2% of runtime)
// ---------------------------------------------------------------------------
__launch_bounds__(256, 2)
__global__ void rnn_zin(const float* __restrict__ inputs, const _Float16* __restrict__ wih16,
                        const float* __restrict__ bih, const float* __restrict__ bhh,
                        float* __restrict__ out) {
  const int wave = threadIdx.x >> 6;
  const int lane = threadIdx.x & 63;
  const int col = lane & 15;
  const int quad = lane >> 4;
  const int m0 = blockIdx.x * 64 + wave * 16;

  floatx4 acc[32];
#pragma unroll
  for (int nt = 0; nt < 32; ++nt) acc[nt] = (floatx4){0.f, 0.f, 0.f, 0.f};

#pragma unroll
  for (int kt = 0; kt < 8; ++kt) {
    const float* ap = inputs + (size_t)(m0 + col) * I_SZ + kt * 32 + quad * 8;
    float4 a0 = *(const float4*)(ap);
    float4 a1 = *(const float4*)(ap + 4);
    half8 af;
    af[0] = (_Float16)a0.x; af[1] = (_Float16)a0.y; af[2] = (_Float16)a0.z; af[3] = (_Float16)a0.w;
    af[4] = (_Float16)a1.x; af[5] = (_Float16)a1.y; af[6] = (_Float16)a1.z; af[7] = (_Float16)a1.w;
#pragma unroll
    for (int nt = 0; nt < 32; ++nt) {
      half8 bf = *(const half8*)(wih16 + (size_t)(nt * 16 + col) * I_SZ + kt * 32 + quad * 8);
      acc[nt] = __builtin_amdgcn_mfma_f32_16x16x32_f16(af, bf, acc[nt], 0, 0, 0);
    }
  }

#pragma unroll
  for (int nt = 0; nt < 32; ++nt) {
    const int j = nt * 16 + col;
    const float bias = bih[j] + bhh[j];
#pragma unroll
    for (int r = 0; r < 4; ++r) {
      const int m = m0 + quad * 4 + r;
      out[(size_t)m * H_SZ + j] = acc[nt][r] + bias;
    }
  }
}

// ---------------------------------------------------------------------------
// Kernel 3: persistent recurrence, TWO timesteps per cross-block exchange.
//
// 8 blocks = 2 batch-groups (gb) x 4 j-slices (slice). Block pins BOTH
//   wRow = W[S_s, :]  (128 j x 512 k)  -> step A:  h_t[S_s] local
//   wCol = W[:, S_s]  (512 j x 128 k)  -> step B:  q^(s)[all j] = W[:,S_s] h_t[S_s]
// (256 VGPRs of W; fits the 512-reg unified file at 1 wave/SIMD.)
// The slice owner folds z_{t+1}[S_s] into its q, so reconstruction
// h_{t+1} = relu(q0+q1+q2+q3) needs NO cross-slice z reads (no out race).
// One flag publish + one poll per TWO steps. q exchanged in f32 (u64 relaxed
// agent-scope atomics, MALL-coherent — same proven fence-free scheme).
// ---------------------------------------------------------------------------
__launch_bounds__(256, 1)
__global__ void rnn_steps(const _Float16* __restrict__ whh16, float* __restrict__ out,
                          const _Float16* __restrict__ h16, u64* __restrict__ qbuf,
                          unsigned* __restrict__ flags) {
  const int tid = threadIdx.x;
  const int wave = tid >> 6;
  const int lane = tid & 63;
  const int col = lane & 15;
  const int quad = lane >> 4;
  const int slice = blockIdx.x & 3;
  const int gb = blockIdx.x >> 2;
  const int j0 = slice * 128;
  const int b = gb * 16 + col;  // global batch for this lane's MFMA column

  // +8 f16 pad per row => lane stride 1040B/272B => start banks 4*(col+quad)%32,
  // b128 reads tile the 32 banks at the 8-phase minimum (no excess conflict).
  __shared__ _Float16 hfull[16][520];  // full h_{t-1} for this group's 16 batches
  __shared__ _Float16 hs[16][136];     // own-slice h_t (128 j, padded)

  unsigned* fs = flags + (size_t)(gb * 4 + slice) * 16;
  unsigned* f0 = flags + (size_t)(gb * 4 + ((slice + 1) & 3)) * 16;
  unsigned* f1 = flags + (size_t)(gb * 4 + ((slice + 2) & 3)) * 16;
  unsigned* f2 = flags + (size_t)(gb * 4 + ((slice + 3) & 3)) * 16;

  // ---- pin W row-slice: A-frags for h_t[S_s], wave covers m-tiles {2w, 2w+1} ----
  half8 wRow[2][16];
#pragma unroll
  for (int mm = 0; mm < 2; ++mm) {
    const int m = j0 + (wave * 2 + mm) * 16 + col;
#pragma unroll
    for (int kt = 0; kt < 16; ++kt)
      wRow[mm][kt] = *(const half8*)(whh16 + (size_t)m * H_SZ + kt * 32 + quad * 8);
  }
  // ---- pin W col-slice: A-frags for q; wave w owns output rows j in [w*128,+128) ----
  half8 wCol[8][4];
#pragma unroll
  for (int jj = 0; jj < 8; ++jj) {
    const int m = wave * 128 + jj * 16 + col;
#pragma unroll
    for (int kt = 0; kt < 4; ++kt)
      wCol[jj][kt] = *(const half8*)(whh16 + (size_t)m * H_SZ + j0 + kt * 32 + quad * 8);
  }

  // ---- h_{-1} = h0 into LDS (written by rnn_init; kernel boundary = coherent) ----
#pragma unroll
  for (int c = 0; c < 16; ++c)
    *(unsigned*)(&hfull[c][2 * tid]) =
        *(const unsigned*)(h16 + (size_t)(gb * 16 + c) * H_SZ + 2 * tid);
  __syncthreads();

  for (int p = 0; p < NPER; ++p) {
    const int t = 2 * p;
    // Prefetch own-slice z for both steps (peer-independent).
    float4 zA[2];
#pragma unroll
    for (int mm = 0; mm < 2; ++mm) {
      const int j = j0 + (wave * 2 + mm) * 16 + quad * 4;
      zA[mm] = *(const float4*)(out + ((size_t)b * S_LEN + t) * H_SZ + j);
    }
    float4 zB[8];
    if (wave == slice) {  // only the owner wave folds z_{t+1}[S_s] into q
#pragma unroll
      for (int jj = 0; jj < 8; ++jj) {
        const int j = j0 + jj * 16 + quad * 4;
        zB[jj] = *(const float4*)(out + ((size_t)b * S_LEN + t + 1) * H_SZ + j);
      }
    }

    // ---- step A: h_t[S_s] = relu(zA + W[S_s,:] h_{t-1}) — h_{t-1} from LDS ----
    floatx4 acc[2][2];  // 2 k-interleaved chains per m-tile for MFMA ILP
#pragma unroll
    for (int mm = 0; mm < 2; ++mm)
#pragma unroll
      for (int e = 0; e < 2; ++e) acc[mm][e] = (floatx4){0.f, 0.f, 0.f, 0.f};
#pragma unroll
    for (int kt = 0; kt < 16; ++kt) {
      const half8 hf = *(const half8*)(&hfull[col][kt * 32 + quad * 8]);
      acc[0][kt & 1] = __builtin_amdgcn_mfma_f32_16x16x32_f16(wRow[0][kt], hf, acc[0][kt & 1], 0, 0, 0);
      acc[1][kt & 1] = __builtin_amdgcn_mfma_f32_16x16x32_f16(wRow[1][kt], hf, acc[1][kt & 1], 0, 0, 0);
    }
    float4 hA[2];
#pragma unroll
    for (int mm = 0; mm < 2; ++mm) {
      const floatx4 s = acc[mm][0] + acc[mm][1];
      hA[mm].x = fmaxf(zA[mm].x + s[0], 0.f);
      hA[mm].y = fmaxf(zA[mm].y + s[1], 0.f);
      hA[mm].z = fmaxf(zA[mm].z + s[2], 0.f);
      hA[mm].w = fmaxf(zA[mm].w + s[3], 0.f);
      union { _Float16 h[4]; u64 q; } pk;
      pk.h[0] = (_Float16)hA[mm].x; pk.h[1] = (_Float16)hA[mm].y;
      pk.h[2] = (_Float16)hA[mm].z; pk.h[3] = (_Float16)hA[mm].w;
      *(u64*)(&hs[col][(wave * 2 + mm) * 16 + quad * 4]) = pk.q;  // stash for step B
    }
    __syncthreads();  // hs ready; all hfull reads of this period done

    // ---- step B: q^(s)[j in wave's 128-range, b] = W[:,S_s] h_t[S_s] (+zB on own rows) ----
    floatx4 accB[8];
#pragma unroll
    for (int jj = 0; jj < 8; ++jj) {
      if (wave == slice)
        accB[jj] = (floatx4){zB[jj].x, zB[jj].y, zB[jj].z, zB[jj].w};
      else
        accB[jj] = (floatx4){0.f, 0.f, 0.f, 0.f};
    }
#pragma unroll
    for (int kt = 0; kt < 4; ++kt) {
      const half8 hsf = *(const half8*)(&hs[col][kt * 32 + quad * 8]);
#pragma unroll
      for (int jj = 0; jj < 8; ++jj)
        accB[jj] = __builtin_amdgcn_mfma_f32_16x16x32_f16(wCol[jj][kt], hsf, accB[jj], 0, 0, 0);
    }

    // ---- publish q (f32 pairs as relaxed agent-scope u64 atomics -> MALL) ----
    // mailbox layout: [parity][gb][slice][b=16][jpair=256] u64
    u64* qo = qbuf + ((size_t)((p & 1) * 8 + gb * 4 + slice)) * 4096;
#pragma unroll
    for (int jj = 0; jj < 8; ++jj) {
      const int idx = col * 256 + wave * 64 + jj * 8 + quad * 2;
      union { float f[2]; u64 q; } lo, hi;
      lo.f[0] = accB[jj][0]; lo.f[1] = accB[jj][1];
      hi.f[0] = accB[jj][2]; hi.f[1] = accB[jj][3];
      __hip_atomic_store(qo + idx, lo.q, __ATOMIC_RELAXED, __HIP_MEMORY_SCOPE_AGENT);
      __hip_atomic_store(qo + idx + 1, hi.q, __ATOMIC_RELAXED, __HIP_MEMORY_SCOPE_AGENT);
    }
    asm volatile("s_waitcnt vmcnt(0)" ::: "memory");  // q globally visible
    __syncthreads();
    if (tid == 0)
      __hip_atomic_store(fs, (unsigned)(p + 1), __ATOMIC_RELAXED, __HIP_MEMORY_SCOPE_AGENT);

    // Delayed own-slice out[t] stores — off the pre-flag critical path.
#pragma unroll
    for (int mm = 0; mm < 2; ++mm) {
      const int j = j0 + (wave * 2 + mm) * 16 + quad * 4;
      *(float4*)(out + ((size_t)b * S_LEN + t) * H_SZ + j) = hA[mm];
    }

    // ---- poll peers: non-short-circuit, all 3 flag loads in flight per iter ----
    const unsigned tgt = (unsigned)(p + 1);
    for (;;) {
      const unsigned a = __hip_atomic_load(f0, __ATOMIC_RELAXED, __HIP_MEMORY_SCOPE_AGENT);
      const unsigned bb = __hip_atomic_load(f1, __ATOMIC_RELAXED, __HIP_MEMORY_SCOPE_AGENT);
      const unsigned cc = __hip_atomic_load(f2, __ATOMIC_RELAXED, __HIP_MEMORY_SCOPE_AGENT);
      if (((a >= tgt) & (bb >= tgt) & (cc >= tgt)) != 0) break;
    }
    asm volatile("" ::: "memory");  // don't hoist q loads above the poll

    // ---- reconstruct full h_{t+1} = relu(q0+q1+q2+q3); thread owns j-pair 2*tid ----
    u64* q0p = qbuf + ((size_t)((p & 1) * 8 + gb * 4 + 0)) * 4096;
    u64* q1p = qbuf + ((size_t)((p & 1) * 8 + gb * 4 + 1)) * 4096;
    u64* q2p = qbuf + ((size_t)((p & 1) * 8 + gb * 4 + 2)) * 4096;
    u64* q3p = qbuf + ((size_t)((p & 1) * 8 + gb * 4 + 3)) * 4096;
#pragma unroll
    for (int hf2 = 0; hf2 < 2; ++hf2) {  // 2 halves => 32 loads (64 VGPRs) in flight
      u64 v0[8], v1[8], v2[8], v3[8];
#pragma unroll
      for (int cc2 = 0; cc2 < 8; ++cc2) {
        const int c = hf2 * 8 + cc2;
        v0[cc2] = __hip_atomic_load(q0p + c * 256 + tid, __ATOMIC_RELAXED, __HIP_MEMORY_SCOPE_AGENT);
        v1[cc2] = __hip_atomic_load(q1p + c * 256 + tid, __ATOMIC_RELAXED, __HIP_MEMORY_SCOPE_AGENT);
        v2[cc2] = __hip_atomic_load(q2p + c * 256 + tid, __ATOMIC_RELAXED, __HIP_MEMORY_SCOPE_AGENT);
        v3[cc2] = __hip_atomic_load(q3p + c * 256 + tid, __ATOMIC_RELAXED, __HIP_MEMORY_SCOPE_AGENT);
      }
#pragma unroll
      for (int cc2 = 0; cc2 < 8; ++cc2) {
        const int c = hf2 * 8 + cc2;
        union { u64 q; float f[2]; } a, b2, c2, d2;
        a.q = v0[cc2]; b2.q = v1[cc2]; c2.q = v2[cc2]; d2.q = v3[cc2];
        // identical expression in every block => bitwise-identical h everywhere
        const float s0 = fmaxf((a.f[0] + b2.f[0]) + (c2.f[0] + d2.f[0]), 0.f);
        const float s1 = fmaxf((a.f[1] + b2.f[1]) + (c2.f[1] + d2.f[1]), 0.f);
        union { _Float16 h[2]; unsigned u; } hp;
        hp.h[0] = (_Float16)s0; hp.h[1] = (_Float16)s1;
        *(unsigned*)(&hfull[c][2 * tid]) = hp.u;
        if (wave == slice) {  // owner wave writes its slice of out[t+1] (and tail)
          *(float2*)(out + ((size_t)(gb * 16 + c) * S_LEN + (t + 1)) * H_SZ + 2 * tid) =
              make_float2(s0, s1);
          if (p == NPER - 1)
            *(float2*)(out + OUT_MAIN + (size_t)(gb * 16 + c) * H_SZ + 2 * tid) =
                make_float2(s0, s1);
        }
      }
    }
    __syncthreads();  // hfull ready for next period's step A
  }
}

extern "C" void kernel_launch(void* const* d_in, const int* in_sizes, int n_in,
                              void* d_out, int out_size, void* d_ws, size_t ws_size,
                              hipStream_t stream) {
  (void)in_sizes; (void)n_in; (void)out_size; (void)ws_size;
  const float* inputs = (const float*)d_in[0];
  const float* h0     = (const float*)d_in[1];
  const float* wih    = (const float*)d_in[2];
  const float* whh    = (const float*)d_in[3];
  const float* bih    = (const float*)d_in[4];
  const float* bhh    = (const float*)d_in[5];
  float* out = (float*)d_out;

  char* ws = (char*)d_ws;
  unsigned* flags  = (unsigned*)(ws);                                   // 512 B
  _Float16* wih16 = (_Float16*)(ws + 512);                              // 256 KB
  _Float16* whh16 = (_Float16*)(ws + 512 + 262144);                     // 512 KB
  _Float16* h16   = (_Float16*)(ws + 512 + 262144 + 524288);            // 32 KB (h0)
  u64*      qbuf  = (u64*)(ws + 512 + 262144 + 524288 + 32768);         // 512 KB

  rnn_init<<<64, 256, 0, stream>>>(wih, whh, h0, wih16, whh16, h16, flags);
  rnn_zin<<<1024, 256, 0, stream>>>(inputs, wih16, bih, bhh, out);
  rnn_steps<<<8, 256, 0, stream>>>(whh16, out, h16, qbuf, flags);
}

// Round 2
// 7929.678 us; speedup vs baseline: 1.5027x; 1.0129x over previous
//
#include <hip/hip_runtime.h>

#define B_SZ 32
#define S_LEN 2048
#define I_SZ 256
#define H_SZ 512
#define OUT_MAIN ((size_t)B_SZ * S_LEN * H_SZ)

#define KT_TOT 16   // 512 k in 16 tiles of 32
#define KT_REG 12   // k-tiles pinned in VGPRs (384 regs/thread)
#define KT_LDS 4    // k-tiles resident in LDS (128 KB)

typedef _Float16 half8 __attribute__((ext_vector_type(8)));
typedef float floatx4 __attribute__((ext_vector_type(4)));
typedef unsigned long long u64;

// ---------------------------------------------------------------------------
// Kernel 1: wih16 (row-major f16), w2 = W_hh in MFMA-fragment-major f16
// (frag id = kt*32+mt, within frag lane-major: element
//  w2[((kt*32+mt)*64+lane)*8+e] = W[mt*16+(lane&15)][kt*32+(lane>>4)*8+e]),
// h16 = f16 h0. No flags — rnn_steps has no inter-block communication.
// ---------------------------------------------------------------------------
__global__ void rnn_init(const float* __restrict__ wih, const float* __restrict__ whh,
                         const float* __restrict__ h0,
                         _Float16* __restrict__ wih16, _Float16* __restrict__ w2,
                         _Float16* __restrict__ h16) {
  int idx = blockIdx.x * blockDim.x + threadIdx.x;
  int stride = gridDim.x * blockDim.x;
  for (int i = idx; i < H_SZ * I_SZ; i += stride) wih16[i] = (_Float16)wih[i];
  for (int o = idx; o < H_SZ * H_SZ; o += stride) {
    const int e = o & 7;
    const int lane = (o >> 3) & 63;
    const int mt = (o >> 9) & 31;
    const int kt = o >> 14;
    const int m = mt * 16 + (lane & 15);
    const int k = kt * 32 + (lane >> 4) * 8 + e;
    w2[o] = (_Float16)whh[(size_t)m * H_SZ + k];
  }
  for (int i = idx; i < B_SZ * H_SZ; i += stride) h16[i] = (_Float16)h0[i];
}

// ---------------------------------------------------------------------------
// Kernel 2: z' = inputs @ W_ih^T + b_ih + b_hh -> d_out in [B,S,H] layout.
// (unchanged)
// ---------------------------------------------------------------------------
__launch_bounds__(256, 2)
__global__ void rnn_zin(const float* __restrict__ inputs, const _Float16* __restrict__ wih16,
                        const float* __restrict__ bih, const float* __restrict__ bhh,
                        float* __restrict__ out) {
  const int wave = threadIdx.x >> 6;
  const int lane = threadIdx.x & 63;
  const int col = lane & 15;
  const int quad = lane >> 4;
  const int m0 = blockIdx.x * 64 + wave * 16;

  floatx4 acc[32];
#pragma unroll
  for (int nt = 0; nt < 32; ++nt) acc[nt] = (floatx4){0.f, 0.f, 0.f, 0.f};

#pragma unroll
  for (int kt = 0; kt < 8; ++kt) {
    const float* ap = inputs + (size_t)(m0 + col) * I_SZ + kt * 32 + quad * 8;
    float4 a0 = *(const float4*)(ap);
    float4 a1 = *(const float4*)(ap + 4);
    half8 af;
    af[0] = (_Float16)a0.x; af[1] = (_Float16)a0.y; af[2] = (_Float16)a0.z; af[3] = (_Float16)a0.w;
    af[4] = (_Float16)a1.x; af[5] = (_Float16)a1.y; af[6] = (_Float16)a1.z; af[7] = (_Float16)a1.w;
#pragma unroll
    for (int nt = 0; nt < 32; ++nt) {
      half8 bf = *(const half8*)(wih16 + (size_t)(nt * 16 + col) * I_SZ + kt * 32 + quad * 8);
      acc[nt] = __builtin_amdgcn_mfma_f32_16x16x32_f16(af, bf, acc[nt], 0, 0, 0);
    }
  }

#pragma unroll
  for (int nt = 0; nt < 32; ++nt) {
    const int j = nt * 16 + col;
    const float bias = bih[j] + bhh[j];
#pragma unroll
    for (int r = 0; r < 4; ++r) {
      const int m = m0 + quad * 4 + r;
      out[(size_t)m * H_SZ + j] = acc[nt][r] + bias;
    }
  }
}

// ---------------------------------------------------------------------------
// Kernel 3: fully CU-local recurrence. Grid = 2 blocks; block gb owns batches
// [gb*16,+16) end-to-end. All of W_hh lives on the CU:
//   kt 0..11  -> VGPRs (8 m-tiles/wave x 12 k-tiles x half8 = 384 regs/thread)
//   kt 12..15 -> LDS (128 KB, fragment-major => per-wave sequential ds_read)
// h (16x512 f16 = 16 KB) lives in LDS, XOR-swizzled (byte ^= (batch&7)<<4) so
// B-fragment reads (all 16 batch rows at one k-range) spread across banks.
// Per step: NO global round-trip on the critical path — z_t prefetched one
// step ahead (recurrence-independent), out stores fire-and-forget.
// ---------------------------------------------------------------------------
__launch_bounds__(256, 1)
__global__ void rnn_steps(const _Float16* __restrict__ w2, float* __restrict__ out,
                          const _Float16* __restrict__ h16) {
  __shared__ _Float16 lds_w[KT_LDS * 32 * 64 * 8];  // 131072 B
  __shared__ _Float16 lds_h[16 * H_SZ];             // 16384 B, swizzled

  const int tid = threadIdx.x;
  const int w = tid >> 6;
  const int lane = tid & 63;
  const int col = lane & 15;
  const int quad = lane >> 4;
  const int gb = blockIdx.x;      // 0..1
  const int b = gb * 16 + col;    // this lane's batch (MFMA B column)

  // ---- stage W k-tiles 12..15 into LDS (linear copy of frag-major tail) ----
  {
    const uint4* src = (const uint4*)(w2 + (size_t)KT_REG * 32 * 64 * 8);
    uint4* dst = (uint4*)lds_w;
    for (int i = tid; i < (KT_LDS * 32 * 64 * 8) / 8; i += 256) dst[i] = src[i];
  }
  // ---- stage h0 into LDS (swizzled) ----
  for (int g = tid; g < 16 * (H_SZ / 4); g += 256) {
    const int c = g >> 7;        // batch row 0..15
    const int j = (g & 127) * 4; // j multiple of 4
    u64 v = *(const u64*)(h16 + (size_t)(gb * 16 + c) * H_SZ + j);
    *(u64*)((char*)lds_h + c * 1024 + ((j * 2) ^ ((c & 7) << 4))) = v;
  }

  // ---- pin W k-tiles 0..11: wave w owns m-tiles w*8 .. w*8+7 ----
  half8 wReg[8][KT_REG];
#pragma unroll
  for (int mt = 0; mt < 8; ++mt)
#pragma unroll
    for (int kt = 0; kt < KT_REG; ++kt)
      wReg[mt][kt] = *(const half8*)(w2 + ((size_t)(kt * 32 + w * 8 + mt) * 64 + lane) * 8);

  __syncthreads();

  // ---- prefetch z for t=0 ----
  float4 zf[8];
#pragma unroll
  for (int mt = 0; mt < 8; ++mt) {
    const int j = w * 128 + mt * 16 + quad * 4;
    zf[mt] = *(const float4*)(out + (size_t)b * S_LEN * H_SZ + j);
  }

#pragma unroll 1
  for (int t = 0; t < S_LEN; ++t) {
    // acc starts at z_t (bias already folded in by rnn_zin)
    floatx4 acc[8];
#pragma unroll
    for (int mt = 0; mt < 8; ++mt)
      acc[mt] = (floatx4){zf[mt].x, zf[mt].y, zf[mt].z, zf[mt].w};

    // issue z prefetch for t+1 (last iter reads the tail region; value unused)
#pragma unroll
    for (int mt = 0; mt < 8; ++mt) {
      const int j = w * 128 + mt * 16 + quad * 4;
      zf[mt] = *(const float4*)(out + ((size_t)b * S_LEN + t + 1) * H_SZ + j);
    }

    // ---- h_t[own 128 rows] = relu(z + W h_{t-1}): 128 MFMA per wave ----
#pragma unroll
    for (int kt = 0; kt < KT_TOT; ++kt) {
      const half8 hf = *(const half8*)((const char*)lds_h + col * 1024 +
                                       ((kt * 64 + quad * 16) ^ ((col & 7) << 4)));
      if (kt < KT_REG) {
#pragma unroll
        for (int mt = 0; mt < 8; ++mt)
          acc[mt] = __builtin_amdgcn_mfma_f32_16x16x32_f16(wReg[mt][kt], hf, acc[mt], 0, 0, 0);
      } else {
#pragma unroll
        for (int mt = 0; mt < 8; ++mt) {
          const half8 wl = *(const half8*)((const char*)lds_w +
              ((size_t)((kt - KT_REG) * 32 + w * 8 + mt) * 64 + lane) * 16);
          acc[mt] = __builtin_amdgcn_mfma_f32_16x16x32_f16(wl, hf, acc[mt], 0, 0, 0);
        }
      }
    }

    __syncthreads();  // all reads of h_{t-1} done before overwrite

    // ---- epilogue: relu, store out[t] (in-place over z), write h_t to LDS ----
#pragma unroll
    for (int mt = 0; mt < 8; ++mt) {
      const int j = w * 128 + mt * 16 + quad * 4;
      float4 hv;
      hv.x = fmaxf(acc[mt][0], 0.f);
      hv.y = fmaxf(acc[mt][1], 0.f);
      hv.z = fmaxf(acc[mt][2], 0.f);
      hv.w = fmaxf(acc[mt][3], 0.f);
      *(float4*)(out + ((size_t)b * S_LEN + t) * H_SZ + j) = hv;
      union { _Float16 h[4]; u64 q; } pk;
      pk.h[0] = (_Float16)hv.x; pk.h[1] = (_Float16)hv.y;
      pk.h[2] = (_Float16)hv.z; pk.h[3] = (_Float16)hv.w;
      *(u64*)((char*)lds_h + col * 1024 + ((j * 2) ^ ((col & 7) << 4))) = pk.q;
      if (t == S_LEN - 1)
        *(float4*)(out + OUT_MAIN + (size_t)b * H_SZ + j) = hv;
    }
    __syncthreads();  // h_t visible to all waves for next step
  }
}

extern "C" void kernel_launch(void* const* d_in, const int* in_sizes, int n_in,
                              void* d_out, int out_size, void* d_ws, size_t ws_size,
                              hipStream_t stream) {
  (void)in_sizes; (void)n_in; (void)out_size; (void)ws_size;
  const float* inputs = (const float*)d_in[0];
  const float* h0     = (const float*)d_in[1];
  const float* wih    = (const float*)d_in[2];
  const float* whh    = (const float*)d_in[3];
  const float* bih    = (const float*)d_in[4];
  const float* bhh    = (const float*)d_in[5];
  float* out = (float*)d_out;

  char* ws = (char*)d_ws;
  _Float16* wih16 = (_Float16*)(ws);                       // 256 KB
  _Float16* w2    = (_Float16*)(ws + 262144);              // 512 KB (frag-major W_hh)
  _Float16* h16   = (_Float16*)(ws + 262144 + 524288);     // 32 KB (f16 h0)

  rnn_init<<<64, 256, 0, stream>>>(wih, whh, h0, wih16, w2, h16);
  rnn_zin<<<1024, 256, 0, stream>>>(inputs, wih16, bih, bhh, out);
  rnn_steps<<<2, 256, 0, stream>>>(w2, out, h16);
}

// Round 3
// 6939.391 us; speedup vs baseline: 1.7172x; 1.1427x over previous
//
#include <hip/hip_runtime.h>

#define B_SZ 32
#define S_LEN 2048
#define I_SZ 256
#define H_SZ 512
#define OUT_MAIN ((size_t)B_SZ * S_LEN * H_SZ)

#define KT_TOT 16   // 512 k in 16 tiles of 32
#define KT_REG 12   // k-tiles pinned in VGPRs/AGPRs (384 reg-slots/thread)
#define KT_LDS 4    // k-tiles resident in LDS (128 KB)

typedef _Float16 half8 __attribute__((ext_vector_type(8)));
typedef float floatx4 __attribute__((ext_vector_type(4)));
typedef unsigned long long u64;

// Raw workgroup barrier with LDS-only drain: the per-step hand-off is pure
// LDS, so global loads/stores may stay in flight across it (unlike
// __syncthreads, which compiles to s_waitcnt vmcnt(0) lgkmcnt(0) + s_barrier
// and serializes HBM/L3 latency into every step). sched_barrier(0) fences
// stop hipcc from migrating ds_read/ds_write across the inline asm.
#define LDS_BARRIER()                                         \
  do {                                                        \
    __builtin_amdgcn_sched_barrier(0);                        \
    asm volatile("s_waitcnt lgkmcnt(0)" ::: "memory");        \
    __builtin_amdgcn_s_barrier();                             \
    __builtin_amdgcn_sched_barrier(0);                        \
  } while (0)

// ---------------------------------------------------------------------------
// Kernel 1: wih16 (row-major f16), w2 = W_hh in MFMA-fragment-major f16
// (frag id = kt*32+mt; within frag lane-major:
//  w2[((kt*32+mt)*64+lane)*8+e] = W[mt*16+(lane&15)][kt*32+(lane>>4)*8+e]),
// h16 = f16 h0.
// ---------------------------------------------------------------------------
__global__ void rnn_init(const float* __restrict__ wih, const float* __restrict__ whh,
                         const float* __restrict__ h0,
                         _Float16* __restrict__ wih16, _Float16* __restrict__ w2,
                         _Float16* __restrict__ h16) {
  int idx = blockIdx.x * blockDim.x + threadIdx.x;
  int stride = gridDim.x * blockDim.x;
  for (int i = idx; i < H_SZ * I_SZ; i += stride) wih16[i] = (_Float16)wih[i];
  for (int o = idx; o < H_SZ * H_SZ; o += stride) {
    const int e = o & 7;
    const int lane = (o >> 3) & 63;
    const int mt = (o >> 9) & 31;
    const int kt = o >> 14;
    const int m = mt * 16 + (lane & 15);
    const int k = kt * 32 + (lane >> 4) * 8 + e;
    w2[o] = (_Float16)whh[(size_t)m * H_SZ + k];
  }
  for (int i = idx; i < B_SZ * H_SZ; i += stride) h16[i] = (_Float16)h0[i];
}

// ---------------------------------------------------------------------------
// Kernel 2: z' = inputs @ W_ih^T + b_ih + b_hh -> d_out in [B,S,H] layout.
// (unchanged)
// ---------------------------------------------------------------------------
__launch_bounds__(256, 2)
__global__ void rnn_zin(const float* __restrict__ inputs, const _Float16* __restrict__ wih16,
                        const float* __restrict__ bih, const float* __restrict__ bhh,
                        float* __restrict__ out) {
  const int wave = threadIdx.x >> 6;
  const int lane = threadIdx.x & 63;
  const int col = lane & 15;
  const int quad = lane >> 4;
  const int m0 = blockIdx.x * 64 + wave * 16;

  floatx4 acc[32];
#pragma unroll
  for (int nt = 0; nt < 32; ++nt) acc[nt] = (floatx4){0.f, 0.f, 0.f, 0.f};

#pragma unroll
  for (int kt = 0; kt < 8; ++kt) {
    const float* ap = inputs + (size_t)(m0 + col) * I_SZ + kt * 32 + quad * 8;
    float4 a0 = *(const float4*)(ap);
    float4 a1 = *(const float4*)(ap + 4);
    half8 af;
    af[0] = (_Float16)a0.x; af[1] = (_Float16)a0.y; af[2] = (_Float16)a0.z; af[3] = (_Float16)a0.w;
    af[4] = (_Float16)a1.x; af[5] = (_Float16)a1.y; af[6] = (_Float16)a1.z; af[7] = (_Float16)a1.w;
#pragma unroll
    for (int nt = 0; nt < 32; ++nt) {
      half8 bf = *(const half8*)(wih16 + (size_t)(nt * 16 + col) * I_SZ + kt * 32 + quad * 8);
      acc[nt] = __builtin_amdgcn_mfma_f32_16x16x32_f16(af, bf, acc[nt], 0, 0, 0);
    }
  }

#pragma unroll
  for (int nt = 0; nt < 32; ++nt) {
    const int j = nt * 16 + col;
    const float bias = bih[j] + bhh[j];
#pragma unroll
    for (int r = 0; r < 4; ++r) {
      const int m = m0 + quad * 4 + r;
      out[(size_t)m * H_SZ + j] = acc[nt][r] + bias;
    }
  }
}

// ---------------------------------------------------------------------------
// Kernel 3: fully CU-local recurrence. Grid = 2 blocks; block gb owns batches
// [gb*16,+16) end-to-end. All of W_hh lives on the CU:
//   kt 0..11  -> registers (8 m-tiles/wave x 12 k-tiles x 4 slots = 384)
//   kt 12..15 -> LDS (128 KB, fragment-major => per-wave linear ds_read_b128)
// h (16x512 f16 = 16 KB) in LDS, XOR-swizzled. Per step: z_t loaded at loop
// top (latency hidden under the MFMA loop), consumed in the epilogue; raw
// lgkm-only barriers keep all global traffic (z loads, out stores) in flight
// across the step boundary.
// ---------------------------------------------------------------------------
__launch_bounds__(256, 1)
__global__ void rnn_steps(const _Float16* __restrict__ w2, float* __restrict__ out,
                          const _Float16* __restrict__ h16) {
  __shared__ _Float16 lds_w[KT_LDS * 32 * 64 * 8];  // 131072 B
  __shared__ _Float16 lds_h[16 * H_SZ];             // 16384 B, swizzled

  const int tid = threadIdx.x;
  const int w = tid >> 6;
  const int lane = tid & 63;
  const int col = lane & 15;
  const int quad = lane >> 4;
  const int gb = blockIdx.x;      // 0..1
  const int b = gb * 16 + col;    // this lane's batch (MFMA B column)

  // ---- stage W k-tiles 12..15 into LDS (linear copy of frag-major tail) ----
  {
    const uint4* src = (const uint4*)(w2 + (size_t)KT_REG * 32 * 64 * 8);
    uint4* dst = (uint4*)lds_w;
    for (int i = tid; i < (KT_LDS * 32 * 64 * 8) / 8; i += 256) dst[i] = src[i];
  }
  // ---- stage h0 into LDS (swizzled) ----
  for (int g = tid; g < 16 * (H_SZ / 4); g += 256) {
    const int c = g >> 7;        // batch row 0..15
    const int j = (g & 127) * 4; // j multiple of 4
    u64 v = *(const u64*)(h16 + (size_t)(gb * 16 + c) * H_SZ + j);
    *(u64*)((char*)lds_h + c * 1024 + ((j * 2) ^ ((c & 7) << 4))) = v;
  }

  // ---- pin W k-tiles 0..11: wave w owns m-tiles w*8 .. w*8+7 ----
  half8 wReg[8][KT_REG];
#pragma unroll
  for (int mt = 0; mt < 8; ++mt)
#pragma unroll
    for (int kt = 0; kt < KT_REG; ++kt)
      wReg[mt][kt] = *(const half8*)(w2 + ((size_t)(kt * 32 + w * 8 + mt) * 64 + lane) * 8);

  __syncthreads();  // one-time full barrier: staging complete

#pragma unroll 1
  for (int t = 0; t < S_LEN; ++t) {
    // ---- issue z_t loads now; ~2500 cyc of MFMA/LDS hides the L3 latency ----
    float4 zf[8];
#pragma unroll
    for (int mt = 0; mt < 8; ++mt) {
      const int j = w * 128 + mt * 16 + quad * 4;
      zf[mt] = *(const float4*)(out + ((size_t)b * S_LEN + t) * H_SZ + j);
    }

    floatx4 acc[8];
#pragma unroll
    for (int mt = 0; mt < 8; ++mt) acc[mt] = (floatx4){0.f, 0.f, 0.f, 0.f};

    // ---- W h_{t-1}: 128 MFMA per wave, B-frags (h) + W-tail from LDS ----
#pragma unroll
    for (int kt = 0; kt < KT_TOT; ++kt) {
      const half8 hf = *(const half8*)((const char*)lds_h + col * 1024 +
                                       ((kt * 64 + quad * 16) ^ ((col & 7) << 4)));
      if (kt < KT_REG) {
#pragma unroll
        for (int mt = 0; mt < 8; ++mt)
          acc[mt] = __builtin_amdgcn_mfma_f32_16x16x32_f16(wReg[mt][kt], hf, acc[mt], 0, 0, 0);
      } else {
#pragma unroll
        for (int mt = 0; mt < 8; ++mt) {
          const half8 wl = *(const half8*)((const char*)lds_w +
              ((size_t)((kt - KT_REG) * 32 + w * 8 + mt) * 64 + lane) * 16);
          acc[mt] = __builtin_amdgcn_mfma_f32_16x16x32_f16(wl, hf, acc[mt], 0, 0, 0);
        }
      }
    }

    LDS_BARRIER();  // all h_{t-1} reads returned; safe to overwrite lds_h

    // ---- epilogue: h = relu(z + acc); out store + LDS h write ----
#pragma unroll
    for (int mt = 0; mt < 8; ++mt) {
      const int j = w * 128 + mt * 16 + quad * 4;
      float4 hv;
      hv.x = fmaxf(zf[mt].x + acc[mt][0], 0.f);
      hv.y = fmaxf(zf[mt].y + acc[mt][1], 0.f);
      hv.z = fmaxf(zf[mt].z + acc[mt][2], 0.f);
      hv.w = fmaxf(zf[mt].w + acc[mt][3], 0.f);
      *(float4*)(out + ((size_t)b * S_LEN + t) * H_SZ + j) = hv;  // in-place z -> h
      union { _Float16 h[4]; u64 q; } pk;
      pk.h[0] = (_Float16)hv.x; pk.h[1] = (_Float16)hv.y;
      pk.h[2] = (_Float16)hv.z; pk.h[3] = (_Float16)hv.w;
      *(u64*)((char*)lds_h + col * 1024 + ((j * 2) ^ ((col & 7) << 4))) = pk.q;
      if (t == S_LEN - 1)
        *(float4*)(out + OUT_MAIN + (size_t)b * H_SZ + j) = hv;  // h_final tail
    }

    LDS_BARRIER();  // h_t visible to all waves for next step
  }
}

extern "C" void kernel_launch(void* const* d_in, const int* in_sizes, int n_in,
                              void* d_out, int out_size, void* d_ws, size_t ws_size,
                              hipStream_t stream) {
  (void)in_sizes; (void)n_in; (void)out_size; (void)ws_size;
  const float* inputs = (const float*)d_in[0];
  const float* h0     = (const float*)d_in[1];
  const float* wih    = (const float*)d_in[2];
  const float* whh    = (const float*)d_in[3];
  const float* bih    = (const float*)d_in[4];
  const float* bhh    = (const float*)d_in[5];
  float* out = (float*)d_out;

  char* ws = (char*)d_ws;
  _Float16* wih16 = (_Float16*)(ws);                       // 256 KB
  _Float16* w2    = (_Float16*)(ws + 262144);              // 512 KB (frag-major W_hh)
  _Float16* h16   = (_Float16*)(ws + 262144 + 524288);     // 32 KB (f16 h0)

  rnn_init<<<64, 256, 0, stream>>>(wih, whh, h0, wih16, w2, h16);
  rnn_zin<<<1024, 256, 0, stream>>>(inputs, wih16, bih, bhh, out);
  rnn_steps<<<2, 256, 0, stream>>>(w2, out, h16);
}

// Round 4
// 6904.488 us; speedup vs baseline: 1.7258x; 1.0051x over previous
//
#include <hip/hip_runtime.h>

#define B_SZ 32
#define S_LEN 2048
#define I_SZ 256
#define H_SZ 512
#define OUT_MAIN ((size_t)B_SZ * S_LEN * H_SZ)

#define KT_TOT 16   // 512 k in 16 tiles of 32
#define KT_REG 12   // k-tiles pinned in regs (4 mt x 12 kt x 4 = 192 regs/thread)
#define KT_LDS 4    // k-tiles resident in LDS (128 KB)

typedef _Float16 half8 __attribute__((ext_vector_type(8)));
typedef float floatx4 __attribute__((ext_vector_type(4)));
typedef unsigned long long u64;

// Raw workgroup barrier with LDS-only drain: the per-step hand-off is pure
// LDS, so global loads/stores may stay in flight across it. sched_barrier(0)
// stops hipcc migrating ds ops across the inline asm (rule #18).
#define LDS_BARRIER()                                         \
  do {                                                        \
    __builtin_amdgcn_sched_barrier(0);                        \
    asm volatile("s_waitcnt lgkmcnt(0)" ::: "memory");        \
    __builtin_amdgcn_s_barrier();                             \
    __builtin_amdgcn_sched_barrier(0);                        \
  } while (0)

// ---------------------------------------------------------------------------
// Kernel 1: wih16 (row-major f16), w2 = W_hh in MFMA-fragment-major f16
// (frag id = kt*32+mt; within frag lane-major:
//  w2[((kt*32+mt)*64+lane)*8+e] = W[mt*16+(lane&15)][kt*32+(lane>>4)*8+e]),
// h16 = f16 h0.
// ---------------------------------------------------------------------------
__global__ void rnn_init(const float* __restrict__ wih, const float* __restrict__ whh,
                         const float* __restrict__ h0,
                         _Float16* __restrict__ wih16, _Float16* __restrict__ w2,
                         _Float16* __restrict__ h16) {
  int idx = blockIdx.x * blockDim.x + threadIdx.x;
  int stride = gridDim.x * blockDim.x;
  for (int i = idx; i < H_SZ * I_SZ; i += stride) wih16[i] = (_Float16)wih[i];
  for (int o = idx; o < H_SZ * H_SZ; o += stride) {
    const int e = o & 7;
    const int lane = (o >> 3) & 63;
    const int mt = (o >> 9) & 31;
    const int kt = o >> 14;
    const int m = mt * 16 + (lane & 15);
    const int k = kt * 32 + (lane >> 4) * 8 + e;
    w2[o] = (_Float16)whh[(size_t)m * H_SZ + k];
  }
  for (int i = idx; i < B_SZ * H_SZ; i += stride) h16[i] = (_Float16)h0[i];
}

// ---------------------------------------------------------------------------
// Kernel 2: z' = inputs @ W_ih^T + b_ih + b_hh -> d_out in [B,S,H] layout.
// (unchanged)
// ---------------------------------------------------------------------------
__launch_bounds__(256, 2)
__global__ void rnn_zin(const float* __restrict__ inputs, const _Float16* __restrict__ wih16,
                        const float* __restrict__ bih, const float* __restrict__ bhh,
                        float* __restrict__ out) {
  const int wave = threadIdx.x >> 6;
  const int lane = threadIdx.x & 63;
  const int col = lane & 15;
  const int quad = lane >> 4;
  const int m0 = blockIdx.x * 64 + wave * 16;

  floatx4 acc[32];
#pragma unroll
  for (int nt = 0; nt < 32; ++nt) acc[nt] = (floatx4){0.f, 0.f, 0.f, 0.f};

#pragma unroll
  for (int kt = 0; kt < 8; ++kt) {
    const float* ap = inputs + (size_t)(m0 + col) * I_SZ + kt * 32 + quad * 8;
    float4 a0 = *(const float4*)(ap);
    float4 a1 = *(const float4*)(ap + 4);
    half8 af;
    af[0] = (_Float16)a0.x; af[1] = (_Float16)a0.y; af[2] = (_Float16)a0.z; af[3] = (_Float16)a0.w;
    af[4] = (_Float16)a1.x; af[5] = (_Float16)a1.y; af[6] = (_Float16)a1.z; af[7] = (_Float16)a1.w;
#pragma unroll
    for (int nt = 0; nt < 32; ++nt) {
      half8 bf = *(const half8*)(wih16 + (size_t)(nt * 16 + col) * I_SZ + kt * 32 + quad * 8);
      acc[nt] = __builtin_amdgcn_mfma_f32_16x16x32_f16(af, bf, acc[nt], 0, 0, 0);
    }
  }

#pragma unroll
  for (int nt = 0; nt < 32; ++nt) {
    const int j = nt * 16 + col;
    const float bias = bih[j] + bhh[j];
#pragma unroll
    for (int r = 0; r < 4; ++r) {
      const int m = m0 + quad * 4 + r;
      out[(size_t)m * H_SZ + j] = acc[nt][r] + bias;
    }
  }
}

// ---------------------------------------------------------------------------
// Kernel 3: fully CU-local recurrence, now 512 threads = 8 waves = 2/SIMD so
// LDS latency on one wave hides under its SIMD-partner's MFMAs. Grid = 2
// blocks; block gb owns batches [gb*16,+16). Wave w owns j in [w*64,+64)
// (4 m-tiles). W_hh on the CU: kt 0..11 in regs (192/thread; 384 KB total),
// kt 12..15 in LDS (128 KB, frag-major). h (16 KB) in LDS, XOR-swizzled.
// z_t loaded at step top (global, rides across lgkm-only barriers).
// ---------------------------------------------------------------------------
__launch_bounds__(512, 2)
__global__ void rnn_steps(const _Float16* __restrict__ w2, float* __restrict__ out,
                          const _Float16* __restrict__ h16) {
  __shared__ _Float16 lds_w[KT_LDS * 32 * 64 * 8];  // 131072 B
  __shared__ _Float16 lds_h[16 * H_SZ];             // 16384 B, swizzled

  const int tid = threadIdx.x;
  const int w = tid >> 6;        // wave 0..7
  const int lane = tid & 63;
  const int col = lane & 15;
  const int quad = lane >> 4;
  const int gb = blockIdx.x;     // 0..1
  const int b = gb * 16 + col;   // this lane's batch (MFMA B column)

  // ---- stage W k-tiles 12..15 into LDS (linear copy of frag-major tail) ----
  {
    const uint4* src = (const uint4*)(w2 + (size_t)KT_REG * 32 * 64 * 8);
    uint4* dst = (uint4*)lds_w;
    for (int i = tid; i < (KT_LDS * 32 * 64 * 8) / 8; i += 512) dst[i] = src[i];
  }
  // ---- stage h0 into LDS (swizzled) ----
  for (int g = tid; g < 16 * (H_SZ / 4); g += 512) {
    const int c = g >> 7;        // batch row 0..15
    const int j = (g & 127) * 4; // j multiple of 4
    u64 v = *(const u64*)(h16 + (size_t)(gb * 16 + c) * H_SZ + j);
    *(u64*)((char*)lds_h + c * 1024 + ((j * 2) ^ ((c & 7) << 4))) = v;
  }

  // ---- pin W k-tiles 0..11: wave w owns m-tiles w*4 .. w*4+3 ----
  half8 wReg[4][KT_REG];
#pragma unroll
  for (int mt = 0; mt < 4; ++mt)
#pragma unroll
    for (int kt = 0; kt < KT_REG; ++kt)
      wReg[mt][kt] = *(const half8*)(w2 + ((size_t)(kt * 32 + w * 4 + mt) * 64 + lane) * 8);

  __syncthreads();  // one-time full barrier: staging complete

#pragma unroll 1
  for (int t = 0; t < S_LEN; ++t) {
    // ---- issue z_t loads now; consumed in the epilogue ~2000 cyc later ----
    float4 zf[4];
#pragma unroll
    for (int mt = 0; mt < 4; ++mt) {
      const int j = w * 64 + mt * 16 + quad * 4;
      zf[mt] = *(const float4*)(out + ((size_t)b * S_LEN + t) * H_SZ + j);
    }

    floatx4 acc[4];
#pragma unroll
    for (int mt = 0; mt < 4; ++mt) acc[mt] = (floatx4){0.f, 0.f, 0.f, 0.f};

    // ---- W h_{t-1}: 64 MFMA per wave; hf + W-tail from LDS ----
    __builtin_amdgcn_s_setprio(1);
#pragma unroll
    for (int kt = 0; kt < KT_TOT; ++kt) {
      const half8 hf = *(const half8*)((const char*)lds_h + col * 1024 +
                                       ((kt * 64 + quad * 16) ^ ((col & 7) << 4)));
      if (kt < KT_REG) {
#pragma unroll
        for (int mt = 0; mt < 4; ++mt)
          acc[mt] = __builtin_amdgcn_mfma_f32_16x16x32_f16(wReg[mt][kt], hf, acc[mt], 0, 0, 0);
      } else {
#pragma unroll
        for (int mt = 0; mt < 4; ++mt) {
          const half8 wl = *(const half8*)((const char*)lds_w +
              ((size_t)((kt - KT_REG) * 32 + w * 4 + mt) * 64 + lane) * 16);
          acc[mt] = __builtin_amdgcn_mfma_f32_16x16x32_f16(wl, hf, acc[mt], 0, 0, 0);
        }
      }
    }
    __builtin_amdgcn_s_setprio(0);

    LDS_BARRIER();  // all h_{t-1} reads returned; safe to overwrite lds_h

    // ---- epilogue: h = relu(z + acc); out store + LDS h write ----
#pragma unroll
    for (int mt = 0; mt < 4; ++mt) {
      const int j = w * 64 + mt * 16 + quad * 4;
      float4 hv;
      hv.x = fmaxf(zf[mt].x + acc[mt][0], 0.f);
      hv.y = fmaxf(zf[mt].y + acc[mt][1], 0.f);
      hv.z = fmaxf(zf[mt].z + acc[mt][2], 0.f);
      hv.w = fmaxf(zf[mt].w + acc[mt][3], 0.f);
      *(float4*)(out + ((size_t)b * S_LEN + t) * H_SZ + j) = hv;  // in-place z -> h
      union { _Float16 h[4]; u64 q; } pk;
      pk.h[0] = (_Float16)hv.x; pk.h[1] = (_Float16)hv.y;
      pk.h[2] = (_Float16)hv.z; pk.h[3] = (_Float16)hv.w;
      *(u64*)((char*)lds_h + col * 1024 + ((j * 2) ^ ((col & 7) << 4))) = pk.q;
      if (t == S_LEN - 1)
        *(float4*)(out + OUT_MAIN + (size_t)b * H_SZ + j) = hv;  // h_final tail
    }

    LDS_BARRIER();  // h_t visible to all waves for next step
  }
}

extern "C" void kernel_launch(void* const* d_in, const int* in_sizes, int n_in,
                              void* d_out, int out_size, void* d_ws, size_t ws_size,
                              hipStream_t stream) {
  (void)in_sizes; (void)n_in; (void)out_size; (void)ws_size;
  const float* inputs = (const float*)d_in[0];
  const float* h0     = (const float*)d_in[1];
  const float* wih    = (const float*)d_in[2];
  const float* whh    = (const float*)d_in[3];
  const float* bih    = (const float*)d_in[4];
  const float* bhh    = (const float*)d_in[5];
  float* out = (float*)d_out;

  char* ws = (char*)d_ws;
  _Float16* wih16 = (_Float16*)(ws);                       // 256 KB
  _Float16* w2    = (_Float16*)(ws + 262144);              // 512 KB (frag-major W_hh)
  _Float16* h16   = (_Float16*)(ws + 262144 + 524288);     // 32 KB (f16 h0)

  rnn_init<<<64, 256, 0, stream>>>(wih, whh, h0, wih16, w2, h16);
  rnn_zin<<<1024, 256, 0, stream>>>(inputs, wih16, bih, bhh, out);
  rnn_steps<<<2, 512, 0, stream>>>(w2, out, h16);
}